// Round 4
// baseline (291.972 us; speedup 1.0000x reference)
//
#include <hip/hip_runtime.h>

// RNN: h_{t+1} = tanh(x_t @ W_ih^T + b_ih + b_hh + h_t @ W_hh^T), out = h_T @ fc_w^T + fc_b
// B=8192, T=512, IN=8, H=16.
//
// Round 4:
//  - 64-thread (1-wave) blocks, NB=4 batch/block: no __syncthreads in hot path
//    (within-wave LDS ops are ordered); grid=2048 blocks = 8 blocks/CU = 2 waves/SIMD.
//  - x tile reads software-pipelined: 8 steps of ds_read_b128 hoisted per group
//    (LDS latency ~120cyc paid once per 8 steps, not per step).
//  - next tile's global loads register-prefetched during compute, ds_written at
//    tile end (no barrier needed, same-wave ordering).
//  - recurrence via DPP row_ror with fmac-foldable form: a = fmaf(dpp(h), w, a)
//    (verified correct in R3: wperm[r] = W_hh[j][(j-r)&15], absmax 3e-5).

#define RNN_B   8192
#define RNN_T   512
#define RNN_IN  8
#define RNN_H   16
#define TC      32                 // timesteps per x tile
#define NB      4                  // batch elements per 64-thread block
#define XSTRIDE 264                // padded floats per xs row (groups land on disjoint banks)

// row_ror:R within 16-lane DPP row: lane i receives h from lane (i-R) & 15.
template<int R>
__device__ __forceinline__ float ror16(float v) {
    return __int_as_float(__builtin_amdgcn_update_dpp(
        0, __float_as_int(v), 0x120 + R, 0xF, 0xF, false));
}

__global__ __launch_bounds__(64, 2) void rnn_fused_kernel(
    const float* __restrict__ x,     // [B, T, IN]
    const float* __restrict__ W_ih,  // [H, IN]
    const float* __restrict__ W_hh,  // [H, H]
    const float* __restrict__ b_ih,  // [H]
    const float* __restrict__ b_hh,  // [H]
    const float* __restrict__ fc_w,  // [1, H]
    const float* __restrict__ fc_b,  // [1]
    float* __restrict__ out)         // [B, 1]
{
    __shared__ float xs[NB * XSTRIDE];   // 4 rows x (32 t x 8 in), padded

    const int tid = (int)threadIdx.x;    // 0..63
    const int j   = tid & 15;            // hidden unit (lane within DPP row)
    const int g   = tid >> 4;            // batch element within block (0..3)
    const int b0  = (int)blockIdx.x * NB;
    const int b   = b0 + g;

    // --- per-lane weights ---
    float wperm[RNN_H];
#pragma unroll
    for (int r = 0; r < RNN_H; ++r) {
        wperm[r] = W_hh[j * RNN_H + ((j - r) & 15)];
    }
    float wih[RNN_IN];
#pragma unroll
    for (int i = 0; i < RNN_IN; i += 4) {
        float4 w = *(const float4*)(W_ih + j * RNN_IN + i);
        wih[i] = w.x; wih[i+1] = w.y; wih[i+2] = w.z; wih[i+3] = w.w;
    }
    const float bias = b_ih[j] + b_hh[j];

    // --- staging lane geometry: lane loads row p(=batch b0+p) float4 #tid ---
    // global: row-contiguous, 64 lanes x 16B coalesced per row.
    // LDS write: xs[p*XSTRIDE + tid*4], stride-1 banks, conflict-free.
    float4 gx[NB];

    // first tile -> LDS (vmcnt wait before ds_write inserted by compiler;
    // ds ops of one wave complete in order, so later reads see the writes)
#pragma unroll
    for (int p = 0; p < NB; ++p) {
        gx[p] = *(const float4*)(x + ((size_t)(b0 + p) * RNN_T + 0) * RNN_IN + tid * 4);
    }
#pragma unroll
    for (int p = 0; p < NB; ++p) {
        *(float4*)(xs + p * XSTRIDE + tid * 4) = gx[p];
    }

    float h = 0.0f;

    for (int t0 = 0; t0 < RNN_T; t0 += TC) {
        const bool more = (t0 + TC) < RNN_T;
        // prefetch next tile into registers (latency hidden behind 32 steps)
        if (more) {
#pragma unroll
            for (int p = 0; p < NB; ++p) {
                gx[p] = *(const float4*)(x + ((size_t)(b0 + p) * RNN_T + (t0 + TC)) * RNN_IN + tid * 4);
            }
        }

        for (int u = 0; u < TC; u += 8) {
            // hoisted LDS reads for 8 steps (16 lanes/group read same addr: broadcast)
            float4 xr[16];
#pragma unroll
            for (int s2 = 0; s2 < 8; ++s2) {
                const float* xp = xs + g * XSTRIDE + (u + s2) * RNN_IN;
                xr[2*s2]   = *(const float4*)(xp);
                xr[2*s2+1] = *(const float4*)(xp + 4);
            }
#pragma unroll
            for (int s2 = 0; s2 < 8; ++s2) {
                const float4 xa = xr[2*s2];
                const float4 xb = xr[2*s2+1];

                // input projection (2 chains) — fmac-able forms
                float a0 = fmaf(xa.x, wih[0], bias);
                a0 = fmaf(xa.y, wih[1], a0);
                a0 = fmaf(xa.z, wih[2], a0);
                a0 = fmaf(xa.w, wih[3], a0);

                float a1 = xb.x * wih[4];
                a1 = fmaf(xb.y, wih[5], a1);
                a1 = fmaf(xb.z, wih[6], a1);
                a1 = fmaf(xb.w, wih[7], a1);

                // recurrence: DPP operand in src0, acc==dst -> v_fmac_f32 dpp foldable
                float a2 = h * wperm[0];                    // r=0: identity
                float a3 = ror16<1>(h) * wperm[1];
                a0 = fmaf(ror16<2>(h),  wperm[2],  a0);
                a1 = fmaf(ror16<3>(h),  wperm[3],  a1);
                a2 = fmaf(ror16<4>(h),  wperm[4],  a2);
                a3 = fmaf(ror16<5>(h),  wperm[5],  a3);
                a0 = fmaf(ror16<6>(h),  wperm[6],  a0);
                a1 = fmaf(ror16<7>(h),  wperm[7],  a1);
                a2 = fmaf(ror16<8>(h),  wperm[8],  a2);
                a3 = fmaf(ror16<9>(h),  wperm[9],  a3);
                a0 = fmaf(ror16<10>(h), wperm[10], a0);
                a1 = fmaf(ror16<11>(h), wperm[11], a1);
                a2 = fmaf(ror16<12>(h), wperm[12], a2);
                a3 = fmaf(ror16<13>(h), wperm[13], a3);
                a0 = fmaf(ror16<14>(h), wperm[14], a0);
                a1 = fmaf(ror16<15>(h), wperm[15], a1);

                const float s = (a0 + a1) + (a2 + a3);

                // tanh(s) = 1 - 2/(exp(2s)+1)
                const float e = __expf(s + s);
                const float r = __builtin_amdgcn_rcpf(e + 1.0f);
                h = fmaf(-2.0f, r, 1.0f);
            }
        }

        // write prefetched next tile (same-wave LDS ordering: all reads above
        // are processed before these writes; no barrier needed in 1-wave block)
        if (more) {
#pragma unroll
            for (int p = 0; p < NB; ++p) {
                *(float4*)(xs + p * XSTRIDE + tid * 4) = gx[p];
            }
        }
    }

    // --- epilogue: out[b] = sum_j fc_w[j] * h_j + fc_b ---
    float v = h * fc_w[j];
    v += __shfl_xor(v, 1);
    v += __shfl_xor(v, 2);
    v += __shfl_xor(v, 4);
    v += __shfl_xor(v, 8);
    if (j == 0) out[b] = v + fc_b[0];
}

extern "C" void kernel_launch(void* const* d_in, const int* in_sizes, int n_in,
                              void* d_out, int out_size, void* d_ws, size_t ws_size,
                              hipStream_t stream)
{
    const float* x    = (const float*)d_in[0];
    const float* W_ih = (const float*)d_in[1];
    const float* W_hh = (const float*)d_in[2];
    const float* b_ih = (const float*)d_in[3];
    const float* b_hh = (const float*)d_in[4];
    const float* fc_w = (const float*)d_in[5];
    const float* fc_b = (const float*)d_in[6];
    float* out = (float*)d_out;

    dim3 grid(RNN_B / NB);   // 2048 blocks of 64 threads
    dim3 block(64);
    rnn_fused_kernel<<<grid, block, 0, stream>>>(x, W_ih, W_hh, b_ih, b_hh, fc_w, fc_b, out);
}

// Round 5
// 273.956 us; speedup vs baseline: 1.0658x; 1.0658x over previous
//
#include <hip/hip_runtime.h>

// RNN: h_{t+1} = tanh(x_t @ W_ih^T + b_ih + b_hh + h_t @ W_hh^T), out = h_T @ fc_w^T + fc_b
// B=8192, T=512, IN=8, H=16.
//
// Round 5: split-K by 2 -> 32 lanes per batch element -> 4096 waves = 4 waves/SIMD
// (R3/R4 had 2 waves/SIMD and were stall-bound; R4 additionally spilled its
// hoisted arrays to scratch: VGPR=32, WRITE_SIZE 31MB).
//
// Lane map: lane = 32*gb + 16*q + j.  Row q=0 computes rotation terms r=0..7 for
// output j; row q=1 computes terms r=8..15. Divergence-free trick: row 1 computes
// outputs (j+8)&15 on EVEN steps and j on ODD steps, which makes its required
// rotation amounts r8=0..7 — identical to row 0 (note ±8 coincide mod 16).
// Its h register then holds h_{j+8} after even steps, h_j after odd steps; the
// weight set and reduction-swizzle mask alternate (xor 24 even / xor 16 odd),
// statically selected in the unrolled loop. Verified-correct R3 mapping
// wperm[r]=W_hh[j][(j-r)&15] is reused with these index shifts.
//
// tanh via exp2/rcp builtins (exactly 1 v_exp_f32 + 1 v_rcp_f32).
// No register arrays beyond float4 (R4 spill fix). x staged to LDS per 32-step
// tile; next tile register-prefetched during compute.

#define RNN_B   8192
#define RNN_T   512
#define RNN_IN  8
#define RNN_H   16
#define TC      32                 // timesteps per x tile
#define ROWS    8                  // batch elements per 256-thread block
#define XST     264                // padded floats per xs row; 264*4=1056B (16B-aligned, +8 banks/row)

// row_ror:R within 16-lane DPP row: lane i receives value from lane (i-R) & 15.
template<int R>
__device__ __forceinline__ float ror16(float v) {
    return __int_as_float(__builtin_amdgcn_update_dpp(
        0, __float_as_int(v), 0x120 + R, 0xF, 0xF, false));
}

__global__ __launch_bounds__(256, 4) void rnn_fused_kernel(
    const float* __restrict__ x,     // [B, T, IN]
    const float* __restrict__ W_ih,  // [H, IN]
    const float* __restrict__ W_hh,  // [H, H]
    const float* __restrict__ b_ih,  // [H]
    const float* __restrict__ b_hh,  // [H]
    const float* __restrict__ fc_w,  // [1, H]
    const float* __restrict__ fc_b,  // [1]
    float* __restrict__ out)         // [B, 1]
{
    __shared__ float xs[ROWS * XST];     // 8 rows x (32 t x 8 in), padded (8448 B)

    const int tid  = (int)threadIdx.x;   // 0..255
    const int lane = tid & 63;
    const int wv   = tid >> 6;           // wave in block (0..3)
    const int j    = lane & 15;          // hidden-unit lane within DPP row
    const int q    = (lane >> 4) & 1;    // k-half (0: r=0..7, 1: r=8..15)
    const int gb   = lane >> 5;          // batch within wave (0..1)
    const int row  = 2 * wv + gb;        // batch row within block (0..7)
    const int b0   = (int)blockIdx.x * ROWS;
    const int b    = b0 + row;

    // --- per-lane weights (two parity sets; row0's sets are identical) ---
    // row0:            out j,    terms r=r8:    W[j][(j-r8)&15]
    // row1 even steps: out j^8,  terms r=8+r8:  W[j^8][(j-r8)&15]
    // row1 odd  steps: out j,    terms r=8+r8:  W[j][((j-r8)&15)^8]
    const int oE = q ? (j ^ 8) : j;      // output unit, even steps
    const int oO = j;                    // output unit, odd steps
    float wrE[8], wrO[8];
#pragma unroll
    for (int r8 = 0; r8 < 8; ++r8) {
        const int col = (j - r8) & 15;
        wrE[r8] = W_hh[oE * RNN_H + col];
        wrO[r8] = W_hh[oO * RNN_H + (q ? (col ^ 8) : col)];
    }
    float wiE[4], wiO[4];
#pragma unroll
    for (int i = 0; i < 4; ++i) {
        wiE[i] = W_ih[oE * RNN_IN + q * 4 + i];
        wiO[i] = W_ih[oO * RNN_IN + q * 4 + i];
    }
    const float biasE = q ? 0.0f : (b_ih[oE] + b_hh[oE]);
    const float biasO = q ? 0.0f : (b_ih[oO] + b_hh[oO]);

    // --- staging geometry: 512 float4 per tile, 2 per thread ---
    const int r0 = tid >> 6,        f0 = tid & 63;          // rows 0..3
    const int r1 = (tid + 256) >> 6;                        // rows 4..7
    const size_t goff0 = ((size_t)(b0 + r0) * RNN_T) * RNN_IN + f0 * 4;
    const size_t goff1 = ((size_t)(b0 + r1) * RNN_T) * RNN_IN + f0 * 4;
    float* const lws0 = xs + r0 * XST + f0 * 4;
    float* const lws1 = xs + r1 * XST + f0 * 4;

    // tile 0 -> LDS
    float4 g0 = *(const float4*)(x + goff0);
    float4 g1 = *(const float4*)(x + goff1);
    *(float4*)lws0 = g0;
    *(float4*)lws1 = g1;

    const float* const xbase = xs + row * XST + q * 4;   // this lane's read base
    const float KTANH = 2.8853900817779268f;             // 2/ln(2)

    float h = 0.0f;

    for (int t0 = 0; t0 < RNN_T; t0 += TC) {
        __syncthreads();                 // staged writes visible
        const bool more = (t0 + TC) < RNN_T;
        if (more) {                      // register-prefetch next tile
            g0 = *(const float4*)(x + goff0 + (size_t)(t0 + TC) * RNN_IN);
            g1 = *(const float4*)(x + goff1 + (size_t)(t0 + TC) * RNN_IN);
        }

        float4 xr = *(const float4*)(xbase);
#pragma unroll
        for (int tt = 0; tt < TC; ++tt) {
            const float4 xn = (tt + 1 < TC) ? *(const float4*)(xbase + (tt + 1) * RNN_IN) : xr;
            const bool even = ((tt & 1) == 0);   // static under full unroll

            const float* wr = even ? wrE : wrO;  // static select per unrolled body
            const float* wi = even ? wiE : wiO;
            const float bias = even ? biasE : biasO;

            // proj chain (4 fma from bias)
            float c0 = fmaf(xr.x, wi[0], bias);
            c0 = fmaf(xr.y, wi[1], c0);
            c0 = fmaf(xr.z, wi[2], c0);
            c0 = fmaf(xr.w, wi[3], c0);

            // recurrence: 8 terms, rotations r8=0..7 (r8=0 is identity)
            float c1 = h * wr[0];
            float c2 = ror16<1>(h) * wr[1];
            c1 = fmaf(ror16<2>(h), wr[2], c1);
            c2 = fmaf(ror16<3>(h), wr[3], c2);
            c1 = fmaf(ror16<4>(h), wr[4], c1);
            c2 = fmaf(ror16<5>(h), wr[5], c2);
            c1 = fmaf(ror16<6>(h), wr[6], c1);
            c2 = fmaf(ror16<7>(h), wr[7], c2);

            const float sp = (c0 + c1) + c2;
            // combine the two k-halves: partner lane differs per parity
            const float s = sp + (even ? __shfl_xor(sp, 24) : __shfl_xor(sp, 16));

            // tanh(s) = 1 - 2/(exp2(s*2*log2e)+1)
            const float e  = __builtin_amdgcn_exp2f(s * KTANH);
            const float rc = __builtin_amdgcn_rcpf(e + 1.0f);
            h = fmaf(-2.0f, rc, 1.0f);

            xr = xn;
        }

        if (more) {
            __syncthreads();             // all reads of current tile done
            *(float4*)lws0 = g0;
            *(float4*)lws1 = g1;
        }
    }

    // --- epilogue: T=512 even -> last step index 511 odd -> both rows hold canonical h_j
    float v = h * fc_w[j];
    v += __shfl_xor(v, 1);
    v += __shfl_xor(v, 2);
    v += __shfl_xor(v, 4);
    v += __shfl_xor(v, 8);
    if ((lane & 31) == 0) out[b] = v + fc_b[0];   // lanes 0 and 32 -> the wave's 2 batches
}

extern "C" void kernel_launch(void* const* d_in, const int* in_sizes, int n_in,
                              void* d_out, int out_size, void* d_ws, size_t ws_size,
                              hipStream_t stream)
{
    const float* x    = (const float*)d_in[0];
    const float* W_ih = (const float*)d_in[1];
    const float* W_hh = (const float*)d_in[2];
    const float* b_ih = (const float*)d_in[3];
    const float* b_hh = (const float*)d_in[4];
    const float* fc_w = (const float*)d_in[5];
    const float* fc_b = (const float*)d_in[6];
    float* out = (float*)d_out;

    dim3 grid(RNN_B / ROWS);   // 1024 blocks
    dim3 block(256);           // 4 waves = 8 batch elements/block; 4096 waves total
    rnn_fused_kernel<<<grid, block, 0, stream>>>(x, W_ih, W_hh, b_ih, b_hh, fc_w, fc_b, out);
}